// Round 1
// baseline (1591.395 us; speedup 1.0000x reference)
//
#include <hip/hip_runtime.h>

// Problem constants (from reference)
#define NN 20000
#define EE 320000
#define FF 75
#define GG 64
#define CC 10
#define LL 5
#define EPS 1e-5f

#define NT 15  // node rows per post_kernel block

__device__ inline void gAtomicAdd(float* p, float v) {
    unsafeAtomicAdd(p, v);
}

// ---------------- CSR construction ----------------

__global__ void count_kernel(const int* __restrict__ col, int* __restrict__ cnt, int E) {
    int e = blockIdx.x * blockDim.x + threadIdx.x;
    if (e < E) atomicAdd(&cnt[col[e]], 1);
}

__global__ __launch_bounds__(1024) void scan_kernel(const int* __restrict__ cnt,
                                                    int* __restrict__ offs,
                                                    int* __restrict__ cursor, int N) {
    __shared__ int sh[1024];
    __shared__ int base_sh;
    int tid = threadIdx.x;
    if (tid == 0) base_sh = 0;
    __syncthreads();
    for (int start = 0; start < N; start += 1024) {
        int i = start + tid;
        int val = (i < N) ? cnt[i] : 0;
        sh[tid] = val;
        __syncthreads();
        for (int d = 1; d < 1024; d <<= 1) {
            int t2 = (tid >= d) ? sh[tid - d] : 0;
            __syncthreads();
            sh[tid] += t2;
            __syncthreads();
        }
        int incl = sh[tid];
        int excl = incl - val;
        int chunk_total = sh[1023];
        int base = base_sh;
        if (i < N) { offs[i] = base + excl; cursor[i] = base + excl; }
        __syncthreads();
        if (tid == 0) base_sh = base + chunk_total;
        __syncthreads();
    }
    if (tid == 0) offs[N] = base_sh;
}

__global__ void fill_kernel(const int* __restrict__ row, const int* __restrict__ col,
                            int* __restrict__ cursor, int* __restrict__ csr, int E) {
    int e = blockIdx.x * blockDim.x + threadIdx.x;
    if (e < E) {
        int c = col[e];
        int pos = atomicAdd(&cursor[c], 1);
        csr[pos] = row[e];
    }
}

// ---------------- degree-derived quantities ----------------

__global__ void dinv_kernel(const int* __restrict__ cnt, float* __restrict__ dinv,
                            float* __restrict__ scal, int N) {
    __shared__ float red[256];
    int i = blockIdx.x * 256 + threadIdx.x;
    float lg = 0.f;
    if (i < N) {
        float c = (float)cnt[i];
        dinv[i] = 1.f / sqrtf(c + 1.f);
        lg = logf(c + 1.f);
    }
    red[threadIdx.x] = lg;
    __syncthreads();
    for (int s = 128; s > 0; s >>= 1) {
        if (threadIdx.x < s) red[threadIdx.x] += red[threadIdx.x + s];
        __syncthreads();
    }
    if (threadIdx.x == 0) gAtomicAdd(&scal[0], red[0]);
}

// ---------------- GCN ----------------

__global__ void xw_kernel(const float* __restrict__ x, const float* __restrict__ gw,
                          float* __restrict__ xw, int N) {
    int idx = blockIdx.x * 256 + threadIdx.x;
    if (idx >= N * FF) return;
    int n = idx / FF, f = idx % FF;
    float acc = 0.f;
#pragma unroll
    for (int k = 0; k < 6; k++) acc += x[n * 6 + k] * gw[k * FF + f];
    xw[idx] = acc;
}

__global__ void gcn_kernel(const float* __restrict__ xw, const float* __restrict__ dinv,
                           const int* __restrict__ offs, const int* __restrict__ csr,
                           const float* __restrict__ gcn_b, const int* __restrict__ cnt,
                           const float* __restrict__ scal,
                           float* __restrict__ h, float* __restrict__ amp,
                           float* __restrict__ att, int N) {
    int i = blockIdx.x;
    int t = threadIdx.x;
    int s0 = offs[i], s1 = offs[i + 1];
    float di = dinv[i];
    if (t < FF) {
        float acc = 0.f;
        for (int k = s0; k < s1; k++) {
            int r = csr[k];
            acc += dinv[r] * xw[r * FF + t];
        }
        h[i * FF + t] = di * acc + di * di * xw[i * FF + t] + gcn_b[t];
    }
    if (t == 0) {
        float al = scal[0] / (float)N;
        float d = fmaxf((float)cnt[i], 1.f);
        float lg = logf(d + 1.f);
        amp[i] = lg / al;
        att[i] = al / lg;
    }
}

// ---------------- per-layer kernels ----------------

// u = h @ Wt + pre_b ; v = h @ Wb
__global__ void uv_kernel(const float* __restrict__ h, const float* __restrict__ wt,
                          const float* __restrict__ wb, const float* __restrict__ pb,
                          float* __restrict__ u, float* __restrict__ v, int N) {
    int idx = blockIdx.x * 256 + threadIdx.x;
    if (idx >= N * FF) return;
    int n = idx / FF, f = idx % FF;
    float au = pb[f], av = 0.f;
    const float* hr = h + n * FF;
    for (int k = 0; k < FF; k++) {
        float hv = hr[k];
        au += hv * wt[k * FF + f];
        av += hv * wb[k * FF + f];
    }
    u[idx] = au;
    v[idx] = av;
}

// per-node aggregation: mean, min, max, std over m_e = u[i] + v[row_e]
__global__ void edge_agg_kernel(const float* __restrict__ u, const float* __restrict__ v,
                                const int* __restrict__ offs, const int* __restrict__ csr,
                                const int* __restrict__ cnt, float* __restrict__ agg, int N) {
    int i = blockIdx.x;
    int t = threadIdx.x;
    if (t >= FF) return;
    int s0 = offs[i], s1 = offs[i + 1];
    float ui = u[i * FF + t];
    float s = 0.f, ss = 0.f, mn = 1e30f, mx = -1e30f;
    for (int k = s0; k < s1; k++) {
        int r = csr[k];
        float m = ui + v[r * FF + t];
        s += m;
        ss += m * m;
        mn = fminf(mn, m);
        mx = fmaxf(mx, m);
    }
    int c = cnt[i];
    float cc = fmaxf((float)c, 1.f);
    float mean = s / cc;
    float msq = ss / cc;
    float stdv = sqrtf(fmaxf(msq - mean * mean, 0.f) + EPS);
    if (c == 0) { mn = 0.f; mx = 0.f; }
    float* a = agg + i * (4 * FF);
    a[t] = mean;
    a[FF + t] = mn;
    a[2 * FF + t] = mx;
    a[3 * FF + t] = stdv;
}

// o = [h | agg | agg*amp | agg*att] @ post_w + post_b ; o2 = o @ lin_w + lin_b
// plus BN partial sums (per-feature sum / sumsq over this block's rows)
__global__ __launch_bounds__(256) void post_kernel(
    const float* __restrict__ h, const float* __restrict__ agg,
    const float* __restrict__ amp, const float* __restrict__ att,
    const float* __restrict__ pw, const float* __restrict__ pb,
    const float* __restrict__ lw, const float* __restrict__ lb,
    float* __restrict__ o2, float* __restrict__ bnsum, float* __restrict__ bnssq, int N) {
    __shared__ __align__(16) float catS[NT * 976];
    __shared__ float oL[NT * FF];
    __shared__ float bs[FF], bq[FF];
    int tid = threadIdx.x;
    int n0 = blockIdx.x * NT;

    if (tid < FF) { bs[tid] = 0.f; bq[tid] = 0.f; }

    // load h part of cat
    for (int idx = tid; idx < NT * FF; idx += 256) {
        int r = idx / FF, j = idx % FF;
        int n = n0 + r;
        catS[r * 976 + j] = (n < N) ? h[n * FF + j] : 0.f;
    }
    // load agg, agg*amp, agg*att
    for (int idx = tid; idx < NT * (4 * FF); idx += 256) {
        int r = idx / (4 * FF), j = idx % (4 * FF);
        int n = n0 + r;
        float a = 0.f, am = 0.f, at = 0.f;
        if (n < N) { a = agg[n * (4 * FF) + j]; am = amp[n]; at = att[n]; }
        catS[r * 976 + FF + j] = a;
        catS[r * 976 + 5 * FF + j] = a * am;
        catS[r * 976 + 9 * FF + j] = a * at;
    }
    __syncthreads();

    int c = tid % FF;
    int rg = tid / FF;  // 0..2 valid when tid < 225
    if (tid < 225) {
        float acc[5];
#pragma unroll
        for (int j = 0; j < 5; j++) acc[j] = pb[c];
        const float* pwc = pw + c;
        int k = 0;
        for (; k + 4 <= 975; k += 4) {
            float w0 = pwc[(k + 0) * FF];
            float w1_ = pwc[(k + 1) * FF];
            float w2_ = pwc[(k + 2) * FF];
            float w3_ = pwc[(k + 3) * FF];
#pragma unroll
            for (int j = 0; j < 5; j++) {
                int r = rg + 3 * j;
                const float4 cv = *reinterpret_cast<const float4*>(&catS[r * 976 + k]);
                acc[j] += cv.x * w0 + cv.y * w1_ + cv.z * w2_ + cv.w * w3_;
            }
        }
        for (; k < 975; k++) {
            float w = pwc[k * FF];
#pragma unroll
            for (int j = 0; j < 5; j++) acc[j] += catS[(rg + 3 * j) * 976 + k] * w;
        }
#pragma unroll
        for (int j = 0; j < 5; j++) oL[(rg + 3 * j) * FF + c] = acc[j];
    }
    __syncthreads();

    if (tid < 225) {
        float acc[5];
#pragma unroll
        for (int j = 0; j < 5; j++) acc[j] = lb[c];
        for (int k = 0; k < FF; k++) {
            float w = lw[k * FF + c];
#pragma unroll
            for (int j = 0; j < 5; j++) acc[j] += oL[(rg + 3 * j) * FF + k] * w;
        }
#pragma unroll
        for (int j = 0; j < 5; j++) {
            int n = n0 + rg + 3 * j;
            if (n < N) {
                float val = acc[j];
                o2[n * FF + c] = val;
                gAtomicAdd(&bs[c], val);
                gAtomicAdd(&bq[c], val * val);
            }
        }
    }
    __syncthreads();
    if (tid < FF) {
        gAtomicAdd(&bnsum[tid], bs[tid]);
        gAtomicAdd(&bnssq[tid], bq[tid]);
    }
}

__global__ void bn_kernel(const float* __restrict__ o2, const float* __restrict__ bnsum,
                          const float* __restrict__ bnssq, const float* __restrict__ bg,
                          const float* __restrict__ bb, float* __restrict__ h, int N) {
    int idx = blockIdx.x * 256 + threadIdx.x;
    if (idx >= N * FF) return;
    int c = idx % FF;
    float mu = bnsum[c] * (1.f / (float)N);
    float var = bnssq[c] * (1.f / (float)N) - mu * mu;
    float val = (o2[idx] - mu) * (1.f / sqrtf(var + EPS)) * bg[c] + bb[c];
    h[idx] = fmaxf(val, 0.f);
}

// ---------------- pooling + final MLP ----------------

__global__ void pool_kernel(const float* __restrict__ h, const int* __restrict__ batch,
                            float* __restrict__ g, int N) {
    __shared__ float acc[GG * FF];
    int n0 = blockIdx.x * 64;
    int n1 = min(n0 + 64, N);
    if (n0 >= N) return;
    int g0 = batch[n0];
    int g1 = batch[n1 - 1];
    int range = g1 - g0 + 1;
    for (int i = threadIdx.x; i < range * FF; i += 256) acc[i] = 0.f;
    __syncthreads();
    int rows = n1 - n0;
    for (int idx = threadIdx.x; idx < rows * FF; idx += 256) {
        int r = idx / FF, c = idx % FF;
        int n = n0 + r;
        gAtomicAdd(&acc[(batch[n] - g0) * FF + c], h[n * FF + c]);
    }
    __syncthreads();
    for (int i = threadIdx.x; i < range * FF; i += 256) gAtomicAdd(&g[g0 * FF + i], acc[i]);
}

__global__ void mlp_kernel(const float* __restrict__ g,
                           const float* __restrict__ w1, const float* __restrict__ b1,
                           const float* __restrict__ w2, const float* __restrict__ b2,
                           const float* __restrict__ w3, const float* __restrict__ b3,
                           float* __restrict__ out) {
    __shared__ float gr[FF], h1[50], h2[25];
    int gi = blockIdx.x, t = threadIdx.x;
    for (int j = t; j < FF; j += 64) gr[j] = g[gi * FF + j];
    __syncthreads();
    if (t < 50) {
        float a = b1[t];
        for (int k = 0; k < FF; k++) a += gr[k] * w1[k * 50 + t];
        h1[t] = fmaxf(a, 0.f);
    }
    __syncthreads();
    if (t < 25) {
        float a = b2[t];
        for (int k = 0; k < 50; k++) a += h1[k] * w2[k * 25 + t];
        h2[t] = fmaxf(a, 0.f);
    }
    __syncthreads();
    if (t < 10) {
        float a = b3[t];
        for (int k = 0; k < 25; k++) a += h2[k] * w3[k * 10 + t];
        out[gi * 10 + t] = a;
    }
}

// ---------------- launch ----------------

extern "C" void kernel_launch(void* const* d_in, const int* in_sizes, int n_in,
                              void* d_out, int out_size, void* d_ws, size_t ws_size,
                              hipStream_t stream) {
    const float* x = (const float*)d_in[0];
    const int* ei = (const int*)d_in[1];
    const int* batch = (const int*)d_in[2];
    const float* gcn_w = (const float*)d_in[3];
    const float* gcn_b = (const float*)d_in[4];
    const float* pre_w = (const float*)d_in[5];
    const float* pre_b = (const float*)d_in[6];
    const float* post_w = (const float*)d_in[7];
    const float* post_b = (const float*)d_in[8];
    const float* lin_w = (const float*)d_in[9];
    const float* lin_b = (const float*)d_in[10];
    const float* bn_g = (const float*)d_in[11];
    const float* bn_b = (const float*)d_in[12];
    const float* w1 = (const float*)d_in[13];
    const float* b1 = (const float*)d_in[14];
    const float* w2 = (const float*)d_in[15];
    const float* b2 = (const float*)d_in[16];
    const float* w3 = (const float*)d_in[17];
    const float* b3 = (const float*)d_in[18];
    float* out = (float*)d_out;

    const int* row = ei;
    const int* col = ei + EE;

    char* ws = (char*)d_ws;
    size_t off = 0;
    auto alloc = [&](size_t bytes) {
        char* p = ws + off;
        off += (bytes + 255) & ~(size_t)255;
        return p;
    };
    int* cnt = (int*)alloc(NN * 4);
    int* offs = (int*)alloc((NN + 1) * 4);
    int* cursor = (int*)alloc(NN * 4);
    int* csr = (int*)alloc(EE * 4);
    float* dinv = (float*)alloc(NN * 4);
    float* amp = (float*)alloc(NN * 4);
    float* att = (float*)alloc(NN * 4);
    float* scal = (float*)alloc((1 + LL * 2 * FF) * 4);  // [0]=sum log; then per-layer bnsum/bnssq
    float* xw = (float*)alloc((size_t)NN * FF * 4);      // aliased as o2 in layers
    float* h = (float*)alloc((size_t)NN * FF * 4);
    float* u = (float*)alloc((size_t)NN * FF * 4);
    float* v = (float*)alloc((size_t)NN * FF * 4);
    float* agg = (float*)alloc((size_t)NN * 4 * FF * 4);
    float* gbuf = (float*)alloc(GG * FF * 4);
    float* o2 = xw;  // xw dead after GCN

    // zero what needs zeroing
    hipMemsetAsync(cnt, 0, NN * 4, stream);
    hipMemsetAsync(scal, 0, (1 + LL * 2 * FF) * 4, stream);
    hipMemsetAsync(gbuf, 0, GG * FF * 4, stream);

    const int B = 256;
    count_kernel<<<(EE + B - 1) / B, B, 0, stream>>>(col, cnt, EE);
    dinv_kernel<<<(NN + B - 1) / B, B, 0, stream>>>(cnt, dinv, scal, NN);
    scan_kernel<<<1, 1024, 0, stream>>>(cnt, offs, cursor, NN);
    fill_kernel<<<(EE + B - 1) / B, B, 0, stream>>>(row, col, cursor, csr, EE);
    xw_kernel<<<(NN * FF + B - 1) / B, B, 0, stream>>>(x, gcn_w, xw, NN);
    gcn_kernel<<<NN, 128, 0, stream>>>(xw, dinv, offs, csr, gcn_b, cnt, scal, h, amp, att, NN);

    for (int l = 0; l < LL; l++) {
        const float* wt = pre_w + (size_t)l * 2 * FF * FF;
        const float* wb = wt + FF * FF;
        const float* pb = pre_b + l * FF;
        const float* pw = post_w + (size_t)l * 13 * FF * FF;
        const float* pob = post_b + l * FF;
        const float* lw = lin_w + (size_t)l * FF * FF;
        const float* lb = lin_b + l * FF;
        float* bnsum = scal + 1 + l * 2 * FF;
        float* bnssq = bnsum + FF;

        uv_kernel<<<(NN * FF + B - 1) / B, B, 0, stream>>>(h, wt, wb, pb, u, v, NN);
        edge_agg_kernel<<<NN, 128, 0, stream>>>(u, v, offs, csr, cnt, agg, NN);
        post_kernel<<<(NN + NT - 1) / NT, 256, 0, stream>>>(h, agg, amp, att, pw, pob, lw, lb,
                                                            o2, bnsum, bnssq, NN);
        bn_kernel<<<(NN * FF + B - 1) / B, B, 0, stream>>>(o2, bnsum, bnssq, bn_g + l * FF,
                                                           bn_b + l * FF, h, NN);
    }

    pool_kernel<<<(NN + 63) / 64, 256, 0, stream>>>(h, batch, gbuf, NN);
    mlp_kernel<<<GG, 64, 0, stream>>>(gbuf, w1, b1, w2, b2, w3, b3, out);
}

// Round 2
// 846.927 us; speedup vs baseline: 1.8790x; 1.8790x over previous
//
#include <hip/hip_runtime.h>
#include <hip/hip_bf16.h>

// Problem constants (from reference)
#define NN 20000
#define EE 320000
#define FF 75
#define GG 64
#define CC 10
#define LL 5
#define EPS 1e-5f

// GEMM paddings
#define KUV 96      // K for uv gemm (h: 75 -> 96)
#define NUV 160     // cols: u at 0..74, v at 80..154
#define KPOST 384   // K for post gemm ([h|agg]: 375 -> 384)
#define NPOST 240   // cols: block0 0..74, block1 80..154, block2 160..234
#define KLIN 96     // K for lin gemm (o: 75 -> 96)
#define NLIN 80

typedef short bf16x8 __attribute__((ext_vector_type(8)));
typedef float f32x4 __attribute__((ext_vector_type(4)));

__device__ inline void gAtomicAdd(float* p, float v) { unsafeAtomicAdd(p, v); }

// ---------------- CSR construction ----------------

__global__ void count_kernel(const int* __restrict__ col, int* __restrict__ cnt, int E) {
    int e = blockIdx.x * blockDim.x + threadIdx.x;
    if (e < E) atomicAdd(&cnt[col[e]], 1);
}

__global__ __launch_bounds__(1024) void scan_kernel(const int* __restrict__ cnt,
                                                    int* __restrict__ offs,
                                                    int* __restrict__ cursor, int N) {
    __shared__ int sh[1024];
    __shared__ int base_sh;
    int tid = threadIdx.x;
    if (tid == 0) base_sh = 0;
    __syncthreads();
    for (int start = 0; start < N; start += 1024) {
        int i = start + tid;
        int val = (i < N) ? cnt[i] : 0;
        sh[tid] = val;
        __syncthreads();
        for (int d = 1; d < 1024; d <<= 1) {
            int t2 = (tid >= d) ? sh[tid - d] : 0;
            __syncthreads();
            sh[tid] += t2;
            __syncthreads();
        }
        int incl = sh[tid];
        int excl = incl - val;
        int chunk_total = sh[1023];
        int base = base_sh;
        if (i < N) { offs[i] = base + excl; cursor[i] = base + excl; }
        __syncthreads();
        if (tid == 0) base_sh = base + chunk_total;
        __syncthreads();
    }
    if (tid == 0) offs[N] = base_sh;
}

__global__ void fill_kernel(const int* __restrict__ row, const int* __restrict__ col,
                            int* __restrict__ cursor, int* __restrict__ csr, int E) {
    int e = blockIdx.x * blockDim.x + threadIdx.x;
    if (e < E) {
        int c = col[e];
        int pos = atomicAdd(&cursor[c], 1);
        csr[pos] = row[e];
    }
}

// ---------------- degree-derived quantities ----------------

__global__ void dinv_kernel(const int* __restrict__ cnt, float* __restrict__ dinv,
                            float* __restrict__ scal, int N) {
    __shared__ float red[256];
    int i = blockIdx.x * 256 + threadIdx.x;
    float lg = 0.f;
    if (i < N) {
        float c = (float)cnt[i];
        dinv[i] = 1.f / sqrtf(c + 1.f);
        lg = logf(c + 1.f);
    }
    red[threadIdx.x] = lg;
    __syncthreads();
    for (int s = 128; s > 0; s >>= 1) {
        if (threadIdx.x < s) red[threadIdx.x] += red[threadIdx.x + s];
        __syncthreads();
    }
    if (threadIdx.x == 0) gAtomicAdd(&scal[0], red[0]);
}

// ---------------- GCN ----------------

__global__ void xw_kernel(const float* __restrict__ x, const float* __restrict__ gw,
                          float* __restrict__ xw, int N) {
    int idx = blockIdx.x * 256 + threadIdx.x;
    if (idx >= N * FF) return;
    int n = idx / FF, f = idx % FF;
    float acc = 0.f;
#pragma unroll
    for (int k = 0; k < 6; k++) acc += x[n * 6 + k] * gw[k * FF + f];
    xw[idx] = acc;
}

// writes h (fp32), hb (bf16 padded to KUV), hagg cols 0..74 (bf16), zero pads
__global__ void gcn_kernel(const float* __restrict__ xw, const float* __restrict__ dinv,
                           const int* __restrict__ offs, const int* __restrict__ csr,
                           const float* __restrict__ gcn_b, const int* __restrict__ cnt,
                           const float* __restrict__ scal,
                           float* __restrict__ h, __hip_bfloat16* __restrict__ hb,
                           __hip_bfloat16* __restrict__ hagg,
                           float* __restrict__ amp, float* __restrict__ att, int N) {
    int i = blockIdx.x;
    int t = threadIdx.x;  // blockDim = 96
    int s0 = offs[i], s1 = offs[i + 1];
    float di = dinv[i];
    if (t < FF) {
        float acc = 0.f;
        for (int k = s0; k < s1; k++) {
            int r = csr[k];
            acc += dinv[r] * xw[r * FF + t];
        }
        float val = di * acc + di * di * xw[i * FF + t] + gcn_b[t];
        h[i * FF + t] = val;
        hb[i * KUV + t] = __float2bfloat16(val);
        hagg[(size_t)i * KPOST + t] = __float2bfloat16(val);
    } else {
        hb[i * KUV + t] = __float2bfloat16(0.f);  // pad cols 75..95
        if (t >= 87) hagg[(size_t)i * KPOST + 375 + (t - 87)] = __float2bfloat16(0.f);
    }
    if (t == 0) {
        float al = scal[0] / (float)N;
        float d = fmaxf((float)cnt[i], 1.f);
        float lg = logf(d + 1.f);
        amp[i] = lg / al;
        att[i] = al / lg;
    }
}

// ---------------- B-matrix prep (all layers, bf16, transposed: BT[col][k]) ----------------

#define S_UV (LL * NUV * KUV)
#define S_POST (LL * NPOST * KPOST)
#define S_LIN (LL * NLIN * KLIN)

__global__ void prep_bt_kernel(const float* __restrict__ pre_w, const float* __restrict__ post_w,
                               const float* __restrict__ lin_w,
                               __hip_bfloat16* __restrict__ BTuv,
                               __hip_bfloat16* __restrict__ BTpost,
                               __hip_bfloat16* __restrict__ BTlin) {
    int idx = blockIdx.x * 256 + threadIdx.x;
    if (idx < S_UV) {
        int l = idx / (NUV * KUV);
        int r = idx % (NUV * KUV);
        int c = r / KUV, k = r % KUV;
        float v = 0.f;
        if (k < FF) {
            if (c < FF) v = pre_w[((size_t)l * 150 + k) * FF + c];
            else if (c >= 80 && c < 80 + FF) v = pre_w[((size_t)l * 150 + FF + k) * FF + (c - 80)];
        }
        BTuv[idx] = __float2bfloat16(v);
    } else if (idx < S_UV + S_POST) {
        int j = idx - S_UV;
        int l = j / (NPOST * KPOST);
        int r = j % (NPOST * KPOST);
        int c = r / KPOST, k = r % KPOST;
        float v = 0.f;
        if (k < FF) {
            if (c < FF) v = post_w[((size_t)l * 975 + k) * FF + c];
        } else if (k < 375) {
            if (c < FF) v = post_w[((size_t)l * 975 + k) * FF + c];
            else if (c >= 80 && c < 80 + FF) v = post_w[((size_t)l * 975 + k + 300) * FF + (c - 80)];
            else if (c >= 160 && c < 160 + FF) v = post_w[((size_t)l * 975 + k + 600) * FF + (c - 160)];
        }
        BTpost[j] = __float2bfloat16(v);
    } else if (idx < S_UV + S_POST + S_LIN) {
        int j = idx - S_UV - S_POST;
        int l = j / (NLIN * KLIN);
        int r = j % (NLIN * KLIN);
        int c = r / KLIN, k = r % KLIN;
        float v = (c < FF && k < FF) ? lin_w[((size_t)l * FF + k) * FF + c] : 0.f;
        BTlin[j] = __float2bfloat16(v);
    }
}

// ---------------- generic bf16 MFMA GEMM ----------------
// C[M x NTILES*16] (fp32) = A[M x KTILES*32] (bf16) @ BT^T, BT is [NTILES*16][KTILES*32] bf16.
// Block: 256 threads = 4 waves; each wave computes 16 rows x all cols. M-tile = 64.
template <int NTILES, int KTILES>
__global__ __launch_bounds__(256) void gemm_kernel(const ushort* __restrict__ A,
                                                   const ushort* __restrict__ BT,
                                                   float* __restrict__ C, int M) {
    constexpr int KS = KTILES * 32;          // global row stride (elems)
    constexpr int NROWS = 64 + NTILES * 16;  // LDS rows (A rows + B cols)
    constexpr int LROW = 40;                 // LDS row stride in elems (80 B, 16B-aligned)
    __shared__ __align__(16) ushort sh[NROWS * LROW];

    int tid = threadIdx.x;
    int w = tid >> 6, lane = tid & 63;
    int n0 = blockIdx.x * 64;

    f32x4 acc[NTILES];
#pragma unroll
    for (int i = 0; i < NTILES; i++) acc[i] = (f32x4){0.f, 0.f, 0.f, 0.f};

    int kseg = (lane >> 4) * 8;
    const ushort* aptr = sh + (w * 16 + (lane & 15)) * LROW + kseg;
    const ushort* bbase = sh + (64 + (lane & 15)) * LROW + kseg;

    for (int kt = 0; kt < KTILES; kt++) {
        int k0 = kt * 32;
        __syncthreads();
        constexpr int SEGS = NROWS * 4;
        for (int s = tid; s < SEGS; s += 256) {
            int r = s >> 2, sg = s & 3;
            uint4 val = {0u, 0u, 0u, 0u};
            if (r < 64) {
                int n = n0 + r;
                if (n < M) val = *(const uint4*)(A + (size_t)n * KS + k0 + sg * 8);
            } else {
                val = *(const uint4*)(BT + (size_t)(r - 64) * KS + k0 + sg * 8);
            }
            *(uint4*)(sh + r * LROW + sg * 8) = val;
        }
        __syncthreads();
        bf16x8 af = *(const bf16x8*)aptr;
#pragma unroll
        for (int nt = 0; nt < NTILES; nt++) {
            bf16x8 bfr = *(const bf16x8*)(bbase + nt * 16 * LROW);
            acc[nt] = __builtin_amdgcn_mfma_f32_16x16x32_bf16(af, bfr, acc[nt], 0, 0, 0);
        }
    }

    int colbase = lane & 15;
    int rbase = w * 16 + ((lane >> 4) << 2);
#pragma unroll
    for (int nt = 0; nt < NTILES; nt++) {
#pragma unroll
        for (int r = 0; r < 4; r++) {
            int n = n0 + rbase + r;
            if (n < M) C[(size_t)n * (NTILES * 16) + nt * 16 + colbase] = acc[nt][r];
        }
    }
}

// ---------------- per-layer helper kernels ----------------

// aggregation over edges; u/v from Cuv fp32 [N, NUV]; writes agg (bf16) into hagg cols 75..374
__global__ void edge_agg_kernel(const float* __restrict__ cuv, const float* __restrict__ pb,
                                const int* __restrict__ offs, const int* __restrict__ csr,
                                const int* __restrict__ cnt,
                                __hip_bfloat16* __restrict__ hagg, int N) {
    int i = blockIdx.x;
    int t = threadIdx.x;
    if (t >= FF) return;
    int s0 = offs[i], s1 = offs[i + 1];
    float ui = cuv[(size_t)i * NUV + t] + pb[t];
    float s = 0.f, ss = 0.f, mn = 1e30f, mx = -1e30f;
    for (int k = s0; k < s1; k++) {
        int r = csr[k];
        float m = ui + cuv[(size_t)r * NUV + 80 + t];
        s += m;
        ss += m * m;
        mn = fminf(mn, m);
        mx = fmaxf(mx, m);
    }
    int c = cnt[i];
    float cc = fmaxf((float)c, 1.f);
    float mean = s / cc;
    float msq = ss / cc;
    float stdv = sqrtf(fmaxf(msq - mean * mean, 0.f) + EPS);
    if (c == 0) { mn = 0.f; mx = 0.f; }
    __hip_bfloat16* a = hagg + (size_t)i * KPOST + FF;
    a[t] = __float2bfloat16(mean);
    a[FF + t] = __float2bfloat16(mn);
    a[2 * FF + t] = __float2bfloat16(mx);
    a[3 * FF + t] = __float2bfloat16(stdv);
}

// o = C1[:,0:75] + amp*C1[:,80:155] + att*C1[:,160:235]  ->  ob (bf16, [N,KLIN] zero-padded)
// (post_b / lin_b cancel exactly under BatchNorm and are omitted)
__global__ void combine_kernel(const float* __restrict__ c1, const float* __restrict__ amp,
                               const float* __restrict__ att, __hip_bfloat16* __restrict__ ob,
                               int N) {
    int idx = blockIdx.x * 256 + threadIdx.x;
    if (idx >= N * KLIN) return;
    int n = idx / KLIN, c = idx % KLIN;
    float v = 0.f;
    if (c < FF) {
        const float* r = c1 + (size_t)n * NPOST;
        v = r[c] + amp[n] * r[80 + c] + att[n] * r[160 + c];
    }
    ob[idx] = __float2bfloat16(v);
}

// per-column sum/ssq of o2 [N, NLIN]
__global__ void bnstat_kernel(const float* __restrict__ o2, float* __restrict__ bnsum,
                              float* __restrict__ bnssq, int N) {
    __shared__ float sA[3][NLIN], sB[3][NLIN];
    int t = threadIdx.x;
    int rg = t / NLIN, c = t % NLIN;
    if (t < 240) {
        float s = 0.f, q = 0.f;
        int n0 = blockIdx.x * 192;
        for (int k = 0; k < 64; k++) {
            int n = n0 + 3 * k + rg;
            if (n < N) {
                float v = o2[(size_t)n * NLIN + c];
                s += v;
                q += v * v;
            }
        }
        sA[rg][c] = s;
        sB[rg][c] = q;
    }
    __syncthreads();
    if (t < FF) {
        gAtomicAdd(&bnsum[t], sA[0][t] + sA[1][t] + sA[2][t]);
        gAtomicAdd(&bnssq[t], sB[0][t] + sB[1][t] + sB[2][t]);
    }
}

// BN + ReLU; writes h (fp32), hb (bf16), hagg col 0..74 (bf16)
__global__ void bn_kernel(const float* __restrict__ o2, const float* __restrict__ bnsum,
                          const float* __restrict__ bnssq, const float* __restrict__ bg,
                          const float* __restrict__ bb, float* __restrict__ h,
                          __hip_bfloat16* __restrict__ hb, __hip_bfloat16* __restrict__ hagg,
                          int N) {
    int idx = blockIdx.x * 256 + threadIdx.x;
    if (idx >= N * FF) return;
    int n = idx / FF, c = idx % FF;
    float mu = bnsum[c] * (1.f / (float)N);
    float var = bnssq[c] * (1.f / (float)N) - mu * mu;
    float val = (o2[(size_t)n * NLIN + c] - mu) * rsqrtf(var + EPS) * bg[c] + bb[c];
    val = fmaxf(val, 0.f);
    h[idx] = val;
    hb[n * KUV + c] = __float2bfloat16(val);
    hagg[(size_t)n * KPOST + c] = __float2bfloat16(val);
}

// ---------------- pooling + final MLP ----------------

__global__ void pool_kernel(const float* __restrict__ h, const int* __restrict__ batch,
                            float* __restrict__ g, int N) {
    __shared__ float acc[GG * FF];
    int n0 = blockIdx.x * 64;
    int n1 = min(n0 + 64, N);
    if (n0 >= N) return;
    int g0 = batch[n0];
    int g1 = batch[n1 - 1];
    int range = g1 - g0 + 1;
    for (int i = threadIdx.x; i < range * FF; i += 256) acc[i] = 0.f;
    __syncthreads();
    int rows = n1 - n0;
    for (int idx = threadIdx.x; idx < rows * FF; idx += 256) {
        int r = idx / FF, c = idx % FF;
        int n = n0 + r;
        gAtomicAdd(&acc[(batch[n] - g0) * FF + c], h[n * FF + c]);
    }
    __syncthreads();
    for (int i = threadIdx.x; i < range * FF; i += 256) gAtomicAdd(&g[g0 * FF + i], acc[i]);
}

__global__ void mlp_kernel(const float* __restrict__ g,
                           const float* __restrict__ w1, const float* __restrict__ b1,
                           const float* __restrict__ w2, const float* __restrict__ b2,
                           const float* __restrict__ w3, const float* __restrict__ b3,
                           float* __restrict__ out) {
    __shared__ float gr[FF], h1[50], h2[25];
    int gi = blockIdx.x, t = threadIdx.x;
    for (int j = t; j < FF; j += 64) gr[j] = g[gi * FF + j];
    __syncthreads();
    if (t < 50) {
        float a = b1[t];
        for (int k = 0; k < FF; k++) a += gr[k] * w1[k * 50 + t];
        h1[t] = fmaxf(a, 0.f);
    }
    __syncthreads();
    if (t < 25) {
        float a = b2[t];
        for (int k = 0; k < 50; k++) a += h1[k] * w2[k * 25 + t];
        h2[t] = fmaxf(a, 0.f);
    }
    __syncthreads();
    if (t < 10) {
        float a = b3[t];
        for (int k = 0; k < 25; k++) a += h2[k] * w3[k * 10 + t];
        out[gi * 10 + t] = a;
    }
}

// ---------------- launch ----------------

extern "C" void kernel_launch(void* const* d_in, const int* in_sizes, int n_in,
                              void* d_out, int out_size, void* d_ws, size_t ws_size,
                              hipStream_t stream) {
    const float* x = (const float*)d_in[0];
    const int* ei = (const int*)d_in[1];
    const int* batch = (const int*)d_in[2];
    const float* gcn_w = (const float*)d_in[3];
    const float* gcn_b = (const float*)d_in[4];
    const float* pre_w = (const float*)d_in[5];
    const float* pre_b = (const float*)d_in[6];
    const float* post_w = (const float*)d_in[7];
    const float* bn_g = (const float*)d_in[11];
    const float* bn_b = (const float*)d_in[12];
    const float* lin_w = (const float*)d_in[9];
    const float* w1 = (const float*)d_in[13];
    const float* b1 = (const float*)d_in[14];
    const float* w2 = (const float*)d_in[15];
    const float* b2 = (const float*)d_in[16];
    const float* w3 = (const float*)d_in[17];
    const float* b3 = (const float*)d_in[18];
    float* out = (float*)d_out;

    const int* row = ei;
    const int* col = ei + EE;

    char* ws = (char*)d_ws;
    size_t off = 0;
    auto alloc = [&](size_t bytes) {
        char* p = ws + off;
        off += (bytes + 255) & ~(size_t)255;
        return p;
    };
    int* cnt = (int*)alloc(NN * 4);
    int* offs = (int*)alloc((NN + 1) * 4);
    int* cursor = (int*)alloc(NN * 4);
    int* csr = (int*)alloc(EE * 4);
    float* dinv = (float*)alloc(NN * 4);
    float* amp = (float*)alloc(NN * 4);
    float* att = (float*)alloc(NN * 4);
    float* scal = (float*)alloc((1 + LL * 2 * NLIN) * 4);  // [0]=sum log; per-layer bnsum/bnssq
    float* h = (float*)alloc((size_t)NN * FF * 4);
    __hip_bfloat16* hb = (__hip_bfloat16*)alloc((size_t)NN * KUV * 2);
    __hip_bfloat16* hagg = (__hip_bfloat16*)alloc((size_t)NN * KPOST * 2);
    __hip_bfloat16* ob = (__hip_bfloat16*)alloc((size_t)NN * KLIN * 2);
    float* big = (float*)alloc((size_t)NN * NPOST * 4);  // xw / Cuv / C1 / o2 (time-disjoint)
    __hip_bfloat16* BTuv = (__hip_bfloat16*)alloc((size_t)S_UV * 2);
    __hip_bfloat16* BTpost = (__hip_bfloat16*)alloc((size_t)S_POST * 2);
    __hip_bfloat16* BTlin = (__hip_bfloat16*)alloc((size_t)S_LIN * 2);
    float* gbuf = (float*)alloc(GG * FF * 4);

    hipMemsetAsync(cnt, 0, NN * 4, stream);
    hipMemsetAsync(scal, 0, (1 + LL * 2 * NLIN) * 4, stream);
    hipMemsetAsync(gbuf, 0, GG * FF * 4, stream);

    const int B = 256;
    count_kernel<<<(EE + B - 1) / B, B, 0, stream>>>(col, cnt, EE);
    dinv_kernel<<<(NN + B - 1) / B, B, 0, stream>>>(cnt, dinv, scal, NN);
    scan_kernel<<<1, 1024, 0, stream>>>(cnt, offs, cursor, NN);
    fill_kernel<<<(EE + B - 1) / B, B, 0, stream>>>(row, col, cursor, csr, EE);
    xw_kernel<<<(NN * FF + B - 1) / B, B, 0, stream>>>(x, gcn_w, big, NN);
    gcn_kernel<<<NN, 96, 0, stream>>>(big, dinv, offs, csr, gcn_b, cnt, scal, h, hb, hagg,
                                      amp, att, NN);
    {
        int tot = S_UV + S_POST + S_LIN;
        prep_bt_kernel<<<(tot + B - 1) / B, B, 0, stream>>>(pre_w, post_w, lin_w,
                                                            BTuv, BTpost, BTlin);
    }

    const int GB = (NN + 63) / 64;  // 313 GEMM blocks
    for (int l = 0; l < LL; l++) {
        float* bnsum = scal + 1 + l * 2 * NLIN;
        float* bnssq = bnsum + NLIN;

        gemm_kernel<NUV / 16, KUV / 32><<<GB, 256, 0, stream>>>(
            (const ushort*)hb, (const ushort*)(BTuv + (size_t)l * NUV * KUV), big, NN);
        edge_agg_kernel<<<NN, 128, 0, stream>>>(big, pre_b + l * FF, offs, csr, cnt, hagg, NN);
        gemm_kernel<NPOST / 16, KPOST / 32><<<GB, 256, 0, stream>>>(
            (const ushort*)hagg, (const ushort*)(BTpost + (size_t)l * NPOST * KPOST), big, NN);
        combine_kernel<<<(NN * KLIN + B - 1) / B, B, 0, stream>>>(big, amp, att, ob, NN);
        gemm_kernel<NLIN / 16, KLIN / 32><<<GB, 256, 0, stream>>>(
            (const ushort*)ob, (const ushort*)(BTlin + (size_t)l * NLIN * KLIN), big, NN);
        bnstat_kernel<<<(NN + 191) / 192, 256, 0, stream>>>(big, bnsum, bnssq, NN);
        bn_kernel<<<(NN * FF + B - 1) / B, B, 0, stream>>>(big, bnsum, bnssq, bn_g + l * FF,
                                                           bn_b + l * FF, h, hb, hagg, NN);
    }

    pool_kernel<<<(NN + 63) / 64, 256, 0, stream>>>(h, batch, gbuf, NN);
    mlp_kernel<<<GG, 64, 0, stream>>>(gbuf, w1, b1, w2, b2, w3, b3, out);
}

// Round 4
// 718.585 us; speedup vs baseline: 2.2146x; 1.1786x over previous
//
#include <hip/hip_runtime.h>
#include <hip/hip_bf16.h>

// Problem constants (from reference)
#define NN 20000
#define EE 320000
#define FF 75
#define GG 64
#define LL 5
#define EPS 1e-5f

// GEMM paddings
#define KUV 96      // K for uv gemm (h: 75 -> 96; col 75 = 1.0 bias trick)
#define NUV 160     // cols: u at 0..74, v at 80..154
#define KPOST 384   // K for post gemm ([h|agg]: 375 -> 384)
#define NPOST 240   // cols: block0 0..74, block1 80..154, block2 160..234
#define KLIN 96

typedef short bf16x8 __attribute__((ext_vector_type(8)));
typedef float f32x4 __attribute__((ext_vector_type(4)));

__device__ inline void gAtomicAdd(float* p, float v) { unsafeAtomicAdd(p, v); }

__device__ inline ushort f2bs(float x) {
    __hip_bfloat16 b = __float2bfloat16(x);
    return *(ushort*)&b;
}

// ---------------- CSR construction ----------------

__global__ void count_kernel(const int* __restrict__ col, int* __restrict__ cnt, int E) {
    int e = blockIdx.x * blockDim.x + threadIdx.x;
    if (e < E) atomicAdd(&cnt[col[e]], 1);
}

__global__ void partial_kernel(const int* __restrict__ cnt, int* __restrict__ bsum, int N) {
    __shared__ int sh[256];
    int tid = threadIdx.x;
    int i = blockIdx.x * 256 + tid;
    sh[tid] = (i < N) ? cnt[i] : 0;
    __syncthreads();
    for (int s = 128; s > 0; s >>= 1) {
        if (tid < s) sh[tid] += sh[tid + s];
        __syncthreads();
    }
    if (tid == 0) bsum[blockIdx.x] = sh[0];
}

__global__ void scanb_kernel(const int* __restrict__ bsum, int* __restrict__ bbase,
                             int* __restrict__ offs, int NB) {
    __shared__ int sh[128];
    int tid = threadIdx.x;
    int v = (tid < NB) ? bsum[tid] : 0;
    sh[tid] = v;
    __syncthreads();
    for (int d = 1; d < 128; d <<= 1) {
        int t = (tid >= d) ? sh[tid - d] : 0;
        __syncthreads();
        sh[tid] += t;
        __syncthreads();
    }
    if (tid < NB) bbase[tid] = sh[tid] - v;
    if (tid == 0) offs[NN] = EE;
}

__global__ void offs_kernel(const int* __restrict__ cnt, const int* __restrict__ bbase,
                            int* __restrict__ offs, int* __restrict__ cursor, int N) {
    __shared__ int sh[256];
    int tid = threadIdx.x;
    int i = blockIdx.x * 256 + tid;
    int v = (i < N) ? cnt[i] : 0;
    sh[tid] = v;
    __syncthreads();
    for (int d = 1; d < 256; d <<= 1) {
        int t = (tid >= d) ? sh[tid - d] : 0;
        __syncthreads();
        sh[tid] += t;
        __syncthreads();
    }
    int excl = sh[tid] - v + bbase[blockIdx.x];
    if (i < N) { offs[i] = excl; cursor[i] = excl; }
}

__global__ void fill_kernel(const int* __restrict__ row, const int* __restrict__ col,
                            int* __restrict__ cursor, int* __restrict__ csr, int E) {
    int e = blockIdx.x * blockDim.x + threadIdx.x;
    if (e < E) {
        int c = col[e];
        int pos = atomicAdd(&cursor[c], 1);
        csr[pos] = row[e];
    }
}

// ---------------- degree-derived quantities ----------------

__global__ void dinv_kernel(const int* __restrict__ cnt, float* __restrict__ dinv,
                            float* __restrict__ scal, int N) {
    __shared__ float red[256];
    int i = blockIdx.x * 256 + threadIdx.x;
    float lg = 0.f;
    if (i < N) {
        float c = (float)cnt[i];
        dinv[i] = 1.f / sqrtf(c + 1.f);
        lg = logf(c + 1.f);
    }
    red[threadIdx.x] = lg;
    __syncthreads();
    for (int s = 128; s > 0; s >>= 1) {
        if (threadIdx.x < s) red[threadIdx.x] += red[threadIdx.x + s];
        __syncthreads();
    }
    if (threadIdx.x == 0) gAtomicAdd(&scal[0], red[0]);
}

// ---------------- GCN ----------------

__global__ void xw_kernel(const float* __restrict__ x, const float* __restrict__ gw,
                          float* __restrict__ xw, int N) {
    int idx = blockIdx.x * 256 + threadIdx.x;
    if (idx >= N * FF) return;
    int n = idx / FF, f = idx % FF;
    float acc = 0.f;
#pragma unroll
    for (int k = 0; k < 6; k++) acc += x[n * 6 + k] * gw[k * FF + f];
    xw[idx] = acc;
}

// writes h (fp32), hb (bf16 [N,96], col75=1.0 bias trick), hagg cols 0..74 + pad
__global__ void gcn_kernel(const float* __restrict__ xw, const float* __restrict__ dinv,
                           const int* __restrict__ offs, const int* __restrict__ csr,
                           const float* __restrict__ gcn_b, const int* __restrict__ cnt,
                           const float* __restrict__ scal,
                           float* __restrict__ h, ushort* __restrict__ hb,
                           ushort* __restrict__ hagg,
                           float* __restrict__ amp, float* __restrict__ att, int N) {
    int i = blockIdx.x;
    int t = threadIdx.x;  // blockDim = 96
    int s0 = offs[i], s1 = offs[i + 1];
    float di = dinv[i];
    if (t < FF) {
        float acc = 0.f;
        for (int k = s0; k < s1; k++) {
            int r = csr[k];
            acc += dinv[r] * xw[r * FF + t];
        }
        float val = di * acc + di * di * xw[i * FF + t] + gcn_b[t];
        h[i * FF + t] = val;
        hb[i * KUV + t] = f2bs(val);
        hagg[(size_t)i * KPOST + t] = f2bs(val);
    } else {
        hb[i * KUV + t] = f2bs(t == FF ? 1.f : 0.f);  // col75 = 1 for bias fold
        if (t >= 87) hagg[(size_t)i * KPOST + 375 + (t - 87)] = 0;
    }
    if (t == 0) {
        float al = scal[0] / (float)N;
        float d = fmaxf((float)cnt[i], 1.f);
        float lg = logf(d + 1.f);
        amp[i] = lg / al;
        att[i] = al / lg;
    }
}

// ---------------- B-matrix prep (bf16, transposed: BT[col][k]) ----------------

#define S_UV (LL * NUV * KUV)
#define S_POST (LL * NPOST * KPOST)
#define S_LIN (LL * NUV / 2 * KLIN)  // 80*96 per layer

__global__ void prep_bt_kernel(const float* __restrict__ pre_w, const float* __restrict__ pre_b,
                               const float* __restrict__ post_w, const float* __restrict__ lin_w,
                               ushort* __restrict__ BTuv, ushort* __restrict__ BTpost,
                               ushort* __restrict__ BTlin) {
    int idx = blockIdx.x * 256 + threadIdx.x;
    if (idx < S_UV) {
        int l = idx / (NUV * KUV);
        int r = idx % (NUV * KUV);
        int c = r / KUV, k = r % KUV;
        float v = 0.f;
        if (k < FF) {
            if (c < FF) v = pre_w[((size_t)l * 150 + k) * FF + c];
            else if (c >= 80 && c < 80 + FF) v = pre_w[((size_t)l * 150 + FF + k) * FF + (c - 80)];
        } else if (k == FF && c < FF) {
            v = pre_b[l * FF + c];  // bias fold: A col75 = 1.0
        }
        BTuv[idx] = f2bs(v);
    } else if (idx < S_UV + S_POST) {
        int j = idx - S_UV;
        int l = j / (NPOST * KPOST);
        int r = j % (NPOST * KPOST);
        int c = r / KPOST, k = r % KPOST;
        float v = 0.f;
        if (k < FF) {
            if (c < FF) v = post_w[((size_t)l * 975 + k) * FF + c];
        } else if (k < 375) {
            if (c < FF) v = post_w[((size_t)l * 975 + k) * FF + c];
            else if (c >= 80 && c < 80 + FF) v = post_w[((size_t)l * 975 + k + 300) * FF + (c - 80)];
            else if (c >= 160 && c < 160 + FF) v = post_w[((size_t)l * 975 + k + 600) * FF + (c - 160)];
        }
        BTpost[j] = f2bs(v);
    } else if (idx < S_UV + S_POST + S_LIN) {
        int j = idx - S_UV - S_POST;
        int l = j / (80 * KLIN);
        int r = j % (80 * KLIN);
        int c = r / KLIN, k = r % KLIN;
        float v = (c < FF && k < FF) ? lin_w[((size_t)l * FF + k) * FF + c] : 0.f;
        BTlin[j] = f2bs(v);
    }
}

// ---------------- uv GEMM: [u|v] = hb @ BTuv^T, compact split epilogue ----------------

__global__ __launch_bounds__(256) void gemm_uv_kernel(const ushort* __restrict__ A,
                                                      const ushort* __restrict__ BT,
                                                      float* __restrict__ U,
                                                      float* __restrict__ V, int M) {
    constexpr int NROWS = 64 + NUV;  // 224
    constexpr int SEGS = NROWS * 4;  // 896
    constexpr int BUF = NROWS * 40;  // 8960 ushorts
    __shared__ __align__(16) ushort sh[2 * BUF];
    int tid = threadIdx.x, w = tid >> 6, lane = tid & 63;
    int col16 = lane & 15, quad = lane >> 4, kseg = quad * 8;
    int n0 = blockIdx.x * 64;

    f32x4 acc[10];
#pragma unroll
    for (int i = 0; i < 10; i++) acc[i] = (f32x4){0.f, 0.f, 0.f, 0.f};

    uint4 pf[4];
    auto loadk = [&](int kt) {
#pragma unroll
        for (int i = 0; i < 4; i++) {
            int s = tid + i * 256;
            if (s < SEGS) {
                int r = s >> 2, sg = s & 3;
                const ushort* src;
                if (r < 64) {
                    int n = min(n0 + r, M - 1);
                    src = A + (size_t)n * KUV + kt * 32 + sg * 8;
                } else {
                    src = BT + (size_t)(r - 64) * KUV + kt * 32 + sg * 8;
                }
                pf[i] = *(const uint4*)src;
            }
        }
    };
    auto storek = [&](ushort* buf) {
#pragma unroll
        for (int i = 0; i < 4; i++) {
            int s = tid + i * 256;
            if (s < SEGS) {
                int r = s >> 2, sg = s & 3;
                *(uint4*)(buf + r * 40 + sg * 8) = pf[i];
            }
        }
    };
    loadk(0);
    storek(sh);
    for (int kt = 0; kt < 3; kt++) {
        __syncthreads();
        const ushort* cur = sh + (kt & 1) * BUF;
        if (kt < 2) loadk(kt + 1);
        bf16x8 af = *(const bf16x8*)(cur + (w * 16 + col16) * 40 + kseg);
#pragma unroll
        for (int nt = 0; nt < 10; nt++) {
            bf16x8 bfr = *(const bf16x8*)(cur + (64 + nt * 16 + col16) * 40 + kseg);
            acc[nt] = __builtin_amdgcn_mfma_f32_16x16x32_bf16(af, bfr, acc[nt], 0, 0, 0);
        }
        if (kt < 2) storek(sh + ((kt + 1) & 1) * BUF);
    }
#pragma unroll
    for (int nt = 0; nt < 10; nt++) {
        int col = nt * 16 + col16;
#pragma unroll
        for (int r = 0; r < 4; r++) {
            int n = n0 + w * 16 + quad * 4 + r;
            if (n < M) {
                if (col < FF) U[(size_t)n * 80 + col] = acc[nt][r];
                else if (col >= 80 && col < 80 + FF) V[(size_t)n * 80 + (col - 80)] = acc[nt][r];
            }
        }
    }
}

// ---------------- fused post GEMM + combine + lin GEMM + bn stats ----------------

__global__ __launch_bounds__(256) void post_fused_kernel(
    const ushort* __restrict__ A, const ushort* __restrict__ BT,
    const ushort* __restrict__ BL, const float* __restrict__ amp,
    const float* __restrict__ att, float* __restrict__ o2,
    float* __restrict__ bnsum, float* __restrict__ bnssq, int M) {
    constexpr int NROWS = 64 + NPOST;  // 304
    constexpr int SEGS = NROWS * 4;    // 1216
    constexpr int BUF = NROWS * 40;    // 12160 ushorts
    __shared__ __align__(16) ushort sh[2 * BUF];  // 48640 B; phase2 aliases this
    __shared__ float bns[80], bnq[80];
    int tid = threadIdx.x, w = tid >> 6, lane = tid & 63;
    int col16 = lane & 15, quad = lane >> 4, kseg = quad * 8;
    int n0 = blockIdx.x * 64;
    if (tid < 80) { bns[tid] = 0.f; bnq[tid] = 0.f; }

    f32x4 acc[15];
#pragma unroll
    for (int i = 0; i < 15; i++) acc[i] = (f32x4){0.f, 0.f, 0.f, 0.f};

    uint4 pf[5];
    auto loadk = [&](int kt) {
#pragma unroll
        for (int i = 0; i < 5; i++) {
            int s = tid + i * 256;
            if (s < SEGS) {
                int r = s >> 2, sg = s & 3;
                const ushort* src;
                if (r < 64) {
                    int n = min(n0 + r, M - 1);
                    src = A + (size_t)n * KPOST + kt * 32 + sg * 8;
                } else {
                    src = BT + (size_t)(r - 64) * KPOST + kt * 32 + sg * 8;
                }
                pf[i] = *(const uint4*)src;
            }
        }
    };
    auto storek = [&](ushort* buf) {
#pragma unroll
        for (int i = 0; i < 5; i++) {
            int s = tid + i * 256;
            if (s < SEGS) {
                int r = s >> 2, sg = s & 3;
                *(uint4*)(buf + r * 40 + sg * 8) = pf[i];
            }
        }
    };
    loadk(0);
    storek(sh);
    for (int kt = 0; kt < 12; kt++) {
        __syncthreads();
        const ushort* cur = sh + (kt & 1) * BUF;
        if (kt < 11) loadk(kt + 1);
        bf16x8 af = *(const bf16x8*)(cur + (w * 16 + col16) * 40 + kseg);
#pragma unroll
        for (int nt = 0; nt < 15; nt++) {
            bf16x8 bfr = *(const bf16x8*)(cur + (64 + nt * 16 + col16) * 40 + kseg);
            acc[nt] = __builtin_amdgcn_mfma_f32_16x16x32_bf16(af, bfr, acc[nt], 0, 0, 0);
        }
        if (kt < 11) storek(sh + ((kt + 1) & 1) * BUF);
    }
    __syncthreads();  // phase-1 LDS reads done; safe to alias

    // ---- phase 2: combine (in-register) -> o (LDS, A-layout) ; lin GEMM ----
    ushort* btl = sh;              // 80 rows x 104 (8320 ushorts)
    ushort* olds = sh + 80 * 104;  // 64 rows x 104 (6656 ushorts)
    // stage BTlin: 80 rows x 96 ushorts = 960 uint4 segments (12 per row)
    for (int s = tid; s < 960; s += 256) {
        int r = s / 12, sg = s % 12;
        *(uint4*)(btl + r * 104 + sg * 8) = *(const uint4*)(BL + r * 96 + sg * 8);
    }
    float ampv[4], attv[4];
#pragma unroll
    for (int r = 0; r < 4; r++) {
        int n = min(n0 + w * 16 + quad * 4 + r, M - 1);
        ampv[r] = amp[n];
        attv[r] = att[n];
    }
#pragma unroll
    for (int nt = 0; nt < 5; nt++) {
        int col = nt * 16 + col16;
#pragma unroll
        for (int r = 0; r < 4; r++) {
            float ov = acc[nt][r] + ampv[r] * acc[nt + 5][r] + attv[r] * acc[nt + 10][r];
            olds[(w * 16 + quad * 4 + r) * 104 + col] = (col < FF) ? f2bs(ov) : (ushort)0;
        }
    }
    for (int s = tid; s < 128; s += 256) {  // zero K-pad cols 80..95
        int r = s >> 1, sg = s & 1;
        *(uint4*)(olds + r * 104 + 80 + sg * 8) = (uint4){0u, 0u, 0u, 0u};
    }
    __syncthreads();

    f32x4 acc2[5];
#pragma unroll
    for (int i = 0; i < 5; i++) acc2[i] = (f32x4){0.f, 0.f, 0.f, 0.f};
#pragma unroll
    for (int k2 = 0; k2 < 3; k2++) {
        bf16x8 af = *(const bf16x8*)(olds + (w * 16 + col16) * 104 + k2 * 32 + kseg);
#pragma unroll
        for (int nt = 0; nt < 5; nt++) {
            bf16x8 bfr = *(const bf16x8*)(btl + (nt * 16 + col16) * 104 + k2 * 32 + kseg);
            acc2[nt] = __builtin_amdgcn_mfma_f32_16x16x32_bf16(af, bfr, acc2[nt], 0, 0, 0);
        }
    }
    // ---- epilogue: store o2 + BN partial sums ----
#pragma unroll
    for (int nt = 0; nt < 5; nt++) {
        int col = nt * 16 + col16;
        float s = 0.f, q = 0.f;
#pragma unroll
        for (int r = 0; r < 4; r++) {
            int n = n0 + w * 16 + quad * 4 + r;
            float v = acc2[nt][r];
            if (n < M && col < FF) {
                o2[(size_t)n * 80 + col] = v;
                s += v;
                q += v * v;
            }
        }
        s += __shfl_xor(s, 16); s += __shfl_xor(s, 32);
        q += __shfl_xor(q, 16); q += __shfl_xor(q, 32);
        if (lane < 16 && col < FF) {
            atomicAdd(&bns[col], s);
            atomicAdd(&bnq[col], q);
        }
    }
    __syncthreads();
    if (tid < FF) {
        gAtomicAdd(&bnsum[tid], bns[tid]);
        gAtomicAdd(&bnssq[tid], bnq[tid]);
    }
}

// ---------------- per-layer helper kernels ----------------

// aggregation over edges; u (bias folded) / v compact fp32 [N,80]
__global__ void edge_agg_kernel(const float* __restrict__ U, const float* __restrict__ V,
                                const int* __restrict__ offs, const int* __restrict__ csr,
                                const int* __restrict__ cnt,
                                ushort* __restrict__ hagg, int N) {
    int i = blockIdx.x;
    int t = threadIdx.x;
    if (t >= FF) return;
    int s0 = offs[i], s1 = offs[i + 1];
    float ui = U[(size_t)i * 80 + t];
    float s = 0.f, ss = 0.f, mn = 1e30f, mx = -1e30f;
    for (int k = s0; k < s1; k++) {
        int r = csr[k];
        float m = ui + V[(size_t)r * 80 + t];
        s += m;
        ss += m * m;
        mn = fminf(mn, m);
        mx = fmaxf(mx, m);
    }
    int c = cnt[i];
    float cc = fmaxf((float)c, 1.f);
    float mean = s / cc;
    float msq = ss / cc;
    float stdv = sqrtf(fmaxf(msq - mean * mean, 0.f) + EPS);
    if (c == 0) { mn = 0.f; mx = 0.f; }
    ushort* a = hagg + (size_t)i * KPOST + FF;
    a[t] = f2bs(mean);
    a[FF + t] = f2bs(mn);
    a[2 * FF + t] = f2bs(mx);
    a[3 * FF + t] = f2bs(stdv);
}

// BN + ReLU; writes h (fp32), hb (bf16), hagg cols 0..74 (bf16)
__global__ void bn_kernel(const float* __restrict__ o2, const float* __restrict__ bnsum,
                          const float* __restrict__ bnssq, const float* __restrict__ bg,
                          const float* __restrict__ bb, float* __restrict__ h,
                          ushort* __restrict__ hb, ushort* __restrict__ hagg, int N) {
    int idx = blockIdx.x * 256 + threadIdx.x;
    if (idx >= N * FF) return;
    int n = idx / FF, c = idx % FF;
    float mu = bnsum[c] * (1.f / (float)N);
    float var = bnssq[c] * (1.f / (float)N) - mu * mu;
    float val = (o2[(size_t)n * 80 + c] - mu) * rsqrtf(var + EPS) * bg[c] + bb[c];
    val = fmaxf(val, 0.f);
    h[idx] = val;
    hb[n * KUV + c] = f2bs(val);
    hagg[(size_t)n * KPOST + c] = f2bs(val);
}

// ---------------- pooling + final MLP ----------------

__global__ void pool_kernel(const float* __restrict__ h, const int* __restrict__ batch,
                            float* __restrict__ g, int N) {
    __shared__ float acc[GG * FF];
    int n0 = blockIdx.x * 64;
    int n1 = min(n0 + 64, N);
    if (n0 >= N) return;
    int g0 = batch[n0];
    int g1 = batch[n1 - 1];
    int range = g1 - g0 + 1;
    for (int i = threadIdx.x; i < range * FF; i += 256) acc[i] = 0.f;
    __syncthreads();
    int rows = n1 - n0;
    for (int idx = threadIdx.x; idx < rows * FF; idx += 256) {
        int r = idx / FF, c = idx % FF;
        int n = n0 + r;
        gAtomicAdd(&acc[(batch[n] - g0) * FF + c], h[n * FF + c]);
    }
    __syncthreads();
    for (int i = threadIdx.x; i < range * FF; i += 256) gAtomicAdd(&g[g0 * FF + i], acc[i]);
}

__global__ void mlp_kernel(const float* __restrict__ g,
                           const float* __restrict__ w1, const float* __restrict__ b1,
                           const float* __restrict__ w2, const float* __restrict__ b2,
                           const float* __restrict__ w3, const float* __restrict__ b3,
                           float* __restrict__ out) {
    __shared__ float gr[FF], h1[50], h2[25];
    int gi = blockIdx.x, t = threadIdx.x;
    for (int j = t; j < FF; j += 64) gr[j] = g[gi * FF + j];
    __syncthreads();
    if (t < 50) {
        float a = b1[t];
        for (int k = 0; k < FF; k++) a += gr[k] * w1[k * 50 + t];
        h1[t] = fmaxf(a, 0.f);
    }
    __syncthreads();
    if (t < 25) {
        float a = b2[t];
        for (int k = 0; k < 50; k++) a += h1[k] * w2[k * 25 + t];
        h2[t] = fmaxf(a, 0.f);
    }
    __syncthreads();
    if (t < 10) {
        float a = b3[t];
        for (int k = 0; k < 25; k++) a += h2[k] * w3[k * 10 + t];
        out[gi * 10 + t] = a;
    }
}

// ---------------- launch ----------------

extern "C" void kernel_launch(void* const* d_in, const int* in_sizes, int n_in,
                              void* d_out, int out_size, void* d_ws, size_t ws_size,
                              hipStream_t stream) {
    const float* x = (const float*)d_in[0];
    const int* ei = (const int*)d_in[1];
    const int* batch = (const int*)d_in[2];
    const float* gcn_w = (const float*)d_in[3];
    const float* gcn_b = (const float*)d_in[4];
    const float* pre_w = (const float*)d_in[5];
    const float* pre_b = (const float*)d_in[6];
    const float* post_w = (const float*)d_in[7];
    const float* lin_w = (const float*)d_in[9];
    const float* bn_g = (const float*)d_in[11];
    const float* bn_b = (const float*)d_in[12];
    const float* w1 = (const float*)d_in[13];
    const float* b1 = (const float*)d_in[14];
    const float* w2 = (const float*)d_in[15];
    const float* b2 = (const float*)d_in[16];
    const float* w3 = (const float*)d_in[17];
    const float* b3 = (const float*)d_in[18];
    float* out = (float*)d_out;

    const int* row = ei;
    const int* col = ei + EE;

    char* ws = (char*)d_ws;
    size_t off = 0;
    auto alloc = [&](size_t bytes) {
        char* p = ws + off;
        off += (bytes + 255) & ~(size_t)255;
        return p;
    };
    int* cnt = (int*)alloc(NN * 4);
    int* offs = (int*)alloc((NN + 1) * 4);
    int* cursor = (int*)alloc(NN * 4);
    int* csr = (int*)alloc(EE * 4);
    int* bsum = (int*)alloc(128 * 4);
    int* bbase = (int*)alloc(128 * 4);
    float* dinv = (float*)alloc(NN * 4);
    float* amp = (float*)alloc(NN * 4);
    float* att = (float*)alloc(NN * 4);
    float* scal = (float*)alloc((1 + LL * 160) * 4);  // [0]=sum log; per-layer bnsum/bnssq
    float* h = (float*)alloc((size_t)NN * FF * 4);
    ushort* hb = (ushort*)alloc((size_t)NN * KUV * 2);
    ushort* hagg = (ushort*)alloc((size_t)NN * KPOST * 2);
    float* ubuf = (float*)alloc((size_t)NN * 80 * 4);
    float* vbuf = (float*)alloc((size_t)NN * 80 * 4);
    float* o2 = (float*)alloc((size_t)NN * 80 * 4);  // also xw scratch in setup
    ushort* BTuv = (ushort*)alloc((size_t)S_UV * 2);
    ushort* BTpost = (ushort*)alloc((size_t)S_POST * 2);
    ushort* BTlin = (ushort*)alloc((size_t)S_LIN * 2);
    float* gbuf = (float*)alloc(GG * FF * 4);

    hipMemsetAsync(cnt, 0, NN * 4, stream);
    hipMemsetAsync(scal, 0, (1 + LL * 160) * 4, stream);
    hipMemsetAsync(gbuf, 0, GG * FF * 4, stream);

    const int B = 256;
    const int NB = (NN + 255) / 256;  // 79
    count_kernel<<<(EE + B - 1) / B, B, 0, stream>>>(col, cnt, EE);
    dinv_kernel<<<NB, B, 0, stream>>>(cnt, dinv, scal, NN);
    partial_kernel<<<NB, B, 0, stream>>>(cnt, bsum, NN);
    scanb_kernel<<<1, 128, 0, stream>>>(bsum, bbase, offs, NB);
    offs_kernel<<<NB, B, 0, stream>>>(cnt, bbase, offs, cursor, NN);
    fill_kernel<<<(EE + B - 1) / B, B, 0, stream>>>(row, col, cursor, csr, EE);
    xw_kernel<<<(NN * FF + B - 1) / B, B, 0, stream>>>(x, gcn_w, o2, NN);
    gcn_kernel<<<NN, 96, 0, stream>>>(o2, dinv, offs, csr, gcn_b, cnt, scal, h, hb, hagg,
                                      amp, att, NN);
    {
        int tot = S_UV + S_POST + S_LIN;
        prep_bt_kernel<<<(tot + B - 1) / B, B, 0, stream>>>(pre_w, pre_b, post_w, lin_w,
                                                            BTuv, BTpost, BTlin);
    }

    const int GB = (NN + 63) / 64;  // 313
    for (int l = 0; l < LL; l++) {
        float* bnsum = scal + 1 + l * 160;
        float* bnssq = bnsum + 80;

        gemm_uv_kernel<<<GB, 256, 0, stream>>>(hb, BTuv + (size_t)l * NUV * KUV, ubuf, vbuf, NN);
        edge_agg_kernel<<<NN, 128, 0, stream>>>(ubuf, vbuf, offs, csr, cnt, hagg, NN);
        post_fused_kernel<<<GB, 256, 0, stream>>>(hagg, BTpost + (size_t)l * NPOST * KPOST,
                                                  BTlin + (size_t)l * 80 * KLIN, amp, att,
                                                  o2, bnsum, bnssq, NN);
        bn_kernel<<<(NN * FF + B - 1) / B, B, 0, stream>>>(o2, bnsum, bnssq, bn_g + l * FF,
                                                           bn_b + l * FF, h, hb, hagg, NN);
    }

    pool_kernel<<<(NN + 63) / 64, 256, 0, stream>>>(h, batch, gbuf, NN);
    mlp_kernel<<<GG, 64, 0, stream>>>(gbuf, w1, b1, w2, b2, w3, b3, out);
}